// Round 1
// baseline (960.116 us; speedup 1.0000x reference)
//
#include <hip/hip_runtime.h>
#include <hip/hip_bf16.h>
#include <cstdint>
#include <cstddef>

#define N_NODES 262143
#define LEAF0   131071
#define N_LEAF  131072
#define HSZ     256
#define XSZ     300
#define KX      320        // XSZ padded to multiple of 32
#define KU      512
#define GATES   1024       // 4*H
#define WCOLS   512        // 2*H
#define BM      128
#define BK      32

typedef short bf16x8 __attribute__((ext_vector_type(8)));
typedef unsigned short u16x8 __attribute__((ext_vector_type(8)));
typedef float f32x4 __attribute__((ext_vector_type(4)));

__device__ __forceinline__ unsigned short f2bf(float f) {
  union { float f; unsigned u; } v; v.f = f;
  unsigned r = v.u + 0x7FFFu + ((v.u >> 16) & 1u);   // RNE
  return (unsigned short)(r >> 16);
}
__device__ __forceinline__ float frcp(float x) { return __builtin_amdgcn_rcpf(x); }
__device__ __forceinline__ float fsig(float x) { return frcp(1.f + __expf(-x)); }
__device__ __forceinline__ float ftanh_(float x) { return 1.f - 2.f * frcp(1.f + __expf(2.f * x)); }

// ---------------------------------------------------------------------------
// Prep: cast + column-permute + transpose W and U into ws (bf16).
// U perm col p = 64*b + 16*g + j  <-  orig col 256*g + 16*b + j   (g=gate, b=out block, j in [0,16))
// W perm col p = 32*b + 16*s + j  <-  orig col 256*s + 16*b + j   (s=0 h / 1 c)
// Stored K-transposed: Ut[p][k] (1024x512), Wt[p][k] (512x320, zero-padded k>=300)
// ---------------------------------------------------------------------------
__global__ void k_prep(const float* __restrict__ W, const float* __restrict__ U,
                       unsigned short* __restrict__ Wt, unsigned short* __restrict__ Ut) {
  int tid = blockIdx.x * blockDim.x + threadIdx.x;
  const int totalU = GATES * KU;
  if (tid < totalU) {
    int p = tid >> 9;          // 0..1023
    int k = tid & 511;
    int g = (p >> 4) & 3, b = p >> 6, j = p & 15;
    int oc = g * 256 + b * 16 + j;
    Ut[tid] = f2bf(U[(size_t)k * GATES + oc]);
  } else {
    int t2 = tid - totalU;
    if (t2 < WCOLS * KX) {
      int p = t2 / KX;
      int k = t2 - p * KX;
      int s = (p >> 4) & 1, b = p >> 5, j = p & 15;
      int oc = s * 256 + b * 16 + j;
      Wt[t2] = (k < XSZ) ? f2bf(W[(size_t)k * WCOLS + oc]) : (unsigned short)0;
    }
  }
}

// ---------------------------------------------------------------------------
// Leaf init: t = tanh(x[leaf] @ W + bW); h=t[:, :256] -> hout, c=t[:,256:] -> cbuf
// M=131072, K=320(300), Nperm=512. 256 thr = 4 waves (2x2), tile 128x128.
// ---------------------------------------------------------------------------
__global__ __launch_bounds__(256) void k_init(
    const float* __restrict__ x, const unsigned short* __restrict__ Wt,
    const float* __restrict__ bW, float* __restrict__ hout, float* __restrict__ cbuf)
{
  __shared__ __attribute__((aligned(16))) unsigned short As[BM][BK];
  __shared__ __attribute__((aligned(16))) unsigned short Bs[BM][BK];
  const int t = threadIdx.x;
  const int lane = t & 63, w = t >> 6;
  const int wm = w >> 1, wn = w & 1;
  const int lr = lane & 15, ls = lane >> 4;
  const int mblk = blockIdx.x >> 2, nblk = blockIdx.x & 3;
  const int tileM = mblk * BM, tileN = nblk * 128;
  const int r = t >> 1, half = t & 1;

  f32x4 acc[4][4];
  #pragma unroll
  for (int i = 0; i < 4; ++i)
    #pragma unroll
    for (int j = 0; j < 4; ++j)
      #pragma unroll
      for (int e = 0; e < 4; ++e) acc[i][j][e] = 0.f;

  const float* Arow = x + (size_t)(LEAF0 + tileM) * XSZ;

  for (int k0 = 0; k0 < KX; k0 += BK) {
    float av[16];
    #pragma unroll
    for (int q = 0; q < 4; ++q) {
      int cbase = k0 + half * 16 + q * 4;
      if (cbase + 4 <= XSZ) {
        const float4 v = *(const float4*)(Arow + (size_t)r * XSZ + cbase);
        av[q*4+0] = v.x; av[q*4+1] = v.y; av[q*4+2] = v.z; av[q*4+3] = v.w;
      } else {
        #pragma unroll
        for (int e = 0; e < 4; ++e) {
          int cc = cbase + e;
          av[q*4+e] = (cc < XSZ) ? Arow[(size_t)r * XSZ + cc] : 0.f;
        }
      }
    }
    u16x8 b0 = *(const u16x8*)(Wt + (size_t)(tileN + r) * KX + k0 + half * 16);
    u16x8 b1 = *(const u16x8*)(Wt + (size_t)(tileN + r) * KX + k0 + half * 16 + 8);
    __syncthreads();
    u16x8 pa0, pa1;
    #pragma unroll
    for (int e = 0; e < 8; ++e) { pa0[e] = f2bf(av[e]); pa1[e] = f2bf(av[8 + e]); }
    *(u16x8*)&As[r][half * 16]     = pa0;
    *(u16x8*)&As[r][half * 16 + 8] = pa1;
    *(u16x8*)&Bs[r][half * 16]     = b0;
    *(u16x8*)&Bs[r][half * 16 + 8] = b1;
    __syncthreads();
    bf16x8 af[4], bfv[4];
    #pragma unroll
    for (int i = 0; i < 4; ++i) af[i]  = *(const bf16x8*)&As[wm * 64 + i * 16 + lr][ls * 8];
    #pragma unroll
    for (int j = 0; j < 4; ++j) bfv[j] = *(const bf16x8*)&Bs[wn * 64 + j * 16 + lr][ls * 8];
    #pragma unroll
    for (int i = 0; i < 4; ++i)
      #pragma unroll
      for (int j = 0; j < 4; ++j)
        acc[i][j] = __builtin_amdgcn_mfma_f32_16x16x32_bf16(af[i], bfv[j], acc[i][j], 0, 0, 0);
  }

  const int pc = tileN + wn * 64;       // perm col base of this wave (of 512)
  #pragma unroll
  for (int i = 0; i < 4; ++i) {
    #pragma unroll
    for (int tt = 0; tt < 2; ++tt) {
      int col = (pc >> 1) + tt * 16 + lr;        // h-dim column 0..255
      #pragma unroll
      for (int rr = 0; rr < 4; ++rr) {
        int row = tileM + wm * 64 + i * 16 + ls * 4 + rr;   // leaf index (grid exact, no mask)
        float th = ftanh_(acc[i][2*tt][rr]   + bW[col]);
        float tc = ftanh_(acc[i][2*tt+1][rr] + bW[256 + col]);
        size_t node = (size_t)LEAF0 + row;
        hout[node * HSZ + col] = th;
        cbuf[node * HSZ + col] = tc;
      }
    }
  }
}

// ---------------------------------------------------------------------------
// One tree level, fully fused: gates = h[2a+1 : 2b+1] (as m x 512) @ Uperm + bU;
// i,o,u,f in-register via gate-permuted N frags; c_new/h_new written directly.
// ---------------------------------------------------------------------------
__global__ __launch_bounds__(256) void k_level(
    float* __restrict__ hbuf,          // d_out: read children h, write own h
    float* __restrict__ cbuf,
    const unsigned short* __restrict__ Ut, const float* __restrict__ bU,
    int a, int m)
{
  __shared__ __attribute__((aligned(16))) unsigned short As[BM][BK];
  __shared__ __attribute__((aligned(16))) unsigned short Bs[BM][BK];
  const int t = threadIdx.x;
  const int lane = t & 63, w = t >> 6;
  const int wm = w >> 1, wn = w & 1;
  const int lr = lane & 15, ls = lane >> 4;
  const int mblk = blockIdx.x >> 3, nblk = blockIdx.x & 7;
  const int tileM = mblk * BM, tileN = nblk * 128;
  const int r = t >> 1, half = t & 1;

  f32x4 acc[4][4];
  #pragma unroll
  for (int i = 0; i < 4; ++i)
    #pragma unroll
    for (int j = 0; j < 4; ++j)
      #pragma unroll
      for (int e = 0; e < 4; ++e) acc[i][j][e] = 0.f;

  const float* Abase = hbuf + (size_t)(2 * a + 1) * HSZ;   // row stride 512 f32 (2 children rows)

  for (int k0 = 0; k0 < KU; k0 += BK) {
    float av[16];
    const float* ap = Abase + (size_t)(tileM + r) * 512 + k0 + half * 16;
    #pragma unroll
    for (int q = 0; q < 4; ++q) {
      const float4 v = *(const float4*)(ap + q * 4);
      av[q*4+0] = v.x; av[q*4+1] = v.y; av[q*4+2] = v.z; av[q*4+3] = v.w;
    }
    u16x8 b0 = *(const u16x8*)(Ut + (size_t)(tileN + r) * KU + k0 + half * 16);
    u16x8 b1 = *(const u16x8*)(Ut + (size_t)(tileN + r) * KU + k0 + half * 16 + 8);
    __syncthreads();
    u16x8 pa0, pa1;
    #pragma unroll
    for (int e = 0; e < 8; ++e) { pa0[e] = f2bf(av[e]); pa1[e] = f2bf(av[8 + e]); }
    *(u16x8*)&As[r][half * 16]     = pa0;
    *(u16x8*)&As[r][half * 16 + 8] = pa1;
    *(u16x8*)&Bs[r][half * 16]     = b0;
    *(u16x8*)&Bs[r][half * 16 + 8] = b1;
    __syncthreads();
    bf16x8 af[4], bfv[4];
    #pragma unroll
    for (int i = 0; i < 4; ++i) af[i]  = *(const bf16x8*)&As[wm * 64 + i * 16 + lr][ls * 8];
    #pragma unroll
    for (int j = 0; j < 4; ++j) bfv[j] = *(const bf16x8*)&Bs[wn * 64 + j * 16 + lr][ls * 8];
    #pragma unroll
    for (int i = 0; i < 4; ++i)
      #pragma unroll
      for (int j = 0; j < 4; ++j)
        acc[i][j] = __builtin_amdgcn_mfma_f32_16x16x32_bf16(af[i], bfv[j], acc[i][j], 0, 0, 0);
  }

  const int pc = tileN + wn * 64;            // perm col base (of 1024); frag nf == gate g
  const int col = (pc >> 2) + lr;            // h-dim column 0..255
  const float bi = bU[col], bo = bU[256 + col], bu = bU[512 + col], bff = bU[768 + col];
  #pragma unroll
  for (int i = 0; i < 4; ++i) {
    #pragma unroll
    for (int rr = 0; rr < 4; ++rr) {
      int noderow = tileM + wm * 64 + i * 16 + ls * 4 + rr;
      if (noderow < m) {
        float iv = fsig (acc[i][0][rr] + bi);
        float ov = fsig (acc[i][1][rr] + bo);
        float uv = ftanh_(acc[i][2][rr] + bu);
        float fv = fsig (acc[i][3][rr] + bff);
        size_t node = (size_t)a + noderow;
        float cl = cbuf[(2 * node + 1) * HSZ + col];
        float cr = cbuf[(2 * node + 2) * HSZ + col];
        float cn = iv * uv + fv * (cl + cr);
        float hn = ov * ftanh_(cn);
        hbuf[node * HSZ + col] = hn;
        cbuf[node * HSZ + col] = cn;
      }
    }
  }
}

// ---------------------------------------------------------------------------
extern "C" void kernel_launch(void* const* d_in, const int* in_sizes, int n_in,
                              void* d_out, int out_size, void* d_ws, size_t ws_size,
                              hipStream_t stream) {
  const float* x  = (const float*)d_in[0];
  const float* W  = (const float*)d_in[1];
  const float* bW = (const float*)d_in[2];
  const float* U  = (const float*)d_in[3];
  const float* bU = (const float*)d_in[4];
  // d_in[5] = children (int32) — structurally 2i+1/2i+2 (complete binary tree), used implicitly.
  float* hout = (float*)d_out;
  char*  ws   = (char*)d_ws;

  float* cbuf = (float*)ws;                                  // 262143*256*4 = 268,434,432 B
  size_t coff = (size_t)N_NODES * HSZ * sizeof(float);
  unsigned short* Ut = (unsigned short*)(ws + coff);          // 1024*512*2 = 1 MiB
  unsigned short* Wt = (unsigned short*)(ws + coff + (size_t)GATES * KU * 2);  // 512*320*2

  const int preptot = GATES * KU + WCOLS * KX;               // 688128 = 2688*256
  hipLaunchKernelGGL(k_prep, dim3((preptot + 255) / 256), dim3(256), 0, stream, W, U, Wt, Ut);

  hipLaunchKernelGGL(k_init, dim3((N_LEAF / BM) * 4), dim3(256), 0, stream,
                     x, Wt, bW, hout, cbuf);

  for (int d = 16; d >= 0; --d) {
    int m = 1 << d;
    int a = m - 1;
    int mb = (m + BM - 1) / BM;
    hipLaunchKernelGGL(k_level, dim3(mb * 8), dim3(256), 0, stream,
                       hout, cbuf, Ut, bU, a, m);
  }
}

// Round 2
// 803.745 us; speedup vs baseline: 1.1946x; 1.1946x over previous
//
#include <hip/hip_runtime.h>
#include <hip/hip_bf16.h>
#include <cstdint>
#include <cstddef>

#define N_NODES 262143
#define LEAF0   131071
#define N_LEAF  131072
#define HSZ     256
#define XSZ     300
#define KX      320        // XSZ padded to multiple of 32
#define KU      512
#define GATES   1024       // 4*H
#define WCOLS   512        // 2*H
#define BM      128
#define BK      32

typedef short bf16x8 __attribute__((ext_vector_type(8)));
typedef unsigned short u16x8 __attribute__((ext_vector_type(8)));
typedef float f32x4 __attribute__((ext_vector_type(4)));

__device__ __forceinline__ unsigned short f2bf(float f) {
  union { float f; unsigned u; } v; v.f = f;
  unsigned r = v.u + 0x7FFFu + ((v.u >> 16) & 1u);   // RNE
  return (unsigned short)(r >> 16);
}
// HW packed f32->bf16 (RNE), 1 inst / 2 values — same rounding as f2bf for finite inputs.
__device__ __forceinline__ unsigned cvt_pk(float lo, float hi) {
  unsigned r;
  asm("v_cvt_pk_bf16_f32 %0, %1, %2" : "=v"(r) : "v"(lo), "v"(hi));
  return r;
}
__device__ __forceinline__ bf16x8 pack8(f32x4 a0, f32x4 a1) {
  union { unsigned u[4]; bf16x8 v; } r;
  r.u[0] = cvt_pk(a0[0], a0[1]);
  r.u[1] = cvt_pk(a0[2], a0[3]);
  r.u[2] = cvt_pk(a1[0], a1[1]);
  r.u[3] = cvt_pk(a1[2], a1[3]);
  return r.v;
}
__device__ __forceinline__ void gld_lds16(const void* g, void* l) {
  __builtin_amdgcn_global_load_lds(
      (const __attribute__((address_space(1))) unsigned*)g,
      (__attribute__((address_space(3))) unsigned*)l, 16, 0, 0);
}
__device__ __forceinline__ float frcp(float x) { return __builtin_amdgcn_rcpf(x); }
__device__ __forceinline__ float fsig(float x) { return frcp(1.f + __expf(-x)); }
__device__ __forceinline__ float ftanh_(float x) { return 1.f - 2.f * frcp(1.f + __expf(2.f * x)); }

// ---------------------------------------------------------------------------
// Prep: cast + column-permute + transpose W and U into ws (bf16).
// U perm col p = 64*b + 16*g + j  <-  orig col 256*g + 16*b + j
// W perm col p = 32*b + 16*s + j  <-  orig col 256*s + 16*b + j
// Stored K-transposed: Ut[p][k] (1024x512), Wt[p][k] (512x320, zero-pad k>=300)
// ---------------------------------------------------------------------------
__global__ void k_prep(const float* __restrict__ W, const float* __restrict__ U,
                       unsigned short* __restrict__ Wt, unsigned short* __restrict__ Ut) {
  int tid = blockIdx.x * blockDim.x + threadIdx.x;
  const int totalU = GATES * KU;
  if (tid < totalU) {
    int p = tid >> 9;
    int k = tid & 511;
    int g = (p >> 4) & 3, b = p >> 6, j = p & 15;
    int oc = g * 256 + b * 16 + j;
    Ut[tid] = f2bf(U[(size_t)k * GATES + oc]);
  } else {
    int t2 = tid - totalU;
    if (t2 < WCOLS * KX) {
      int p = t2 / KX;
      int k = t2 - p * KX;
      int s = (p >> 4) & 1, b = p >> 5, j = p & 15;
      int oc = s * 256 + b * 16 + j;
      Wt[t2] = (k < XSZ) ? f2bf(W[(size_t)k * WCOLS + oc]) : (unsigned short)0;
    }
  }
}

// ---------------------------------------------------------------------------
// Leaf init: t = tanh(x[leaf] @ W + bW); h -> hout(f32), c -> cbuf(f32)
// m97-style: global_load_lds staging, A = x f32 (cvt at frag read), B = Wt bf16.
// ---------------------------------------------------------------------------
__global__ __launch_bounds__(256) void k_init(
    const float* __restrict__ x, const unsigned short* __restrict__ Wt,
    const float* __restrict__ bW, float* __restrict__ hout, float* __restrict__ cbuf)
{
  __shared__ __attribute__((aligned(16))) float          As[BM * BK];   // 16 KB
  __shared__ __attribute__((aligned(16))) unsigned short Bs[BM * BK];   //  8 KB
  const int t = threadIdx.x;
  const int lane = t & 63, w = t >> 6;
  const int wm = w >> 1, wn = w & 1;
  const int lr = lane & 15, ls = lane >> 4;

  // XCD swizzle: same-mblk blocks adjacent within an XCD chunk (nwg % 8 == 0)
  const int nwg = gridDim.x;
  const int wg = (blockIdx.x & 7) * (nwg >> 3) + (blockIdx.x >> 3);
  const int mblk = wg >> 2, nblk = wg & 3;
  const int tileM = mblk * BM, tileN = nblk * 128;

  f32x4 acc[4][4];
  #pragma unroll
  for (int i = 0; i < 4; ++i)
    #pragma unroll
    for (int j = 0; j < 4; ++j)
      #pragma unroll
      for (int e = 0; e < 4; ++e) acc[i][j][e] = 0.f;

  const int arow = lane >> 3, acolv = (lane & 7) * 4;   // A: 8 rows/issue, 4 f32/lane
  const int brow = lane >> 2, bcolv = (lane & 3) * 8;   // B: 16 rows/issue, 8 bf16/lane

  for (int k0 = 0; k0 < KX; k0 += BK) {
    #pragma unroll
    for (int s = 0; s < 4; ++s) {                        // A: 16 issues total
      int e = w * 4 + s;
      int col = k0 + acolv;
      if (col >= XSZ) col = 0;                           // pad lanes: garbage * Wt(0) = 0
      const float* g = x + (size_t)(LEAF0 + tileM + e * 8 + arow) * XSZ + col;
      gld_lds16(g, (char*)As + e * 1024);
    }
    #pragma unroll
    for (int s = 0; s < 2; ++s) {                        // B: 8 issues total
      int e = w * 2 + s;
      const unsigned short* g = Wt + (size_t)(tileN + e * 16 + brow) * KX + k0 + bcolv;
      gld_lds16(g, (char*)Bs + e * 1024);
    }
    __syncthreads();
    bf16x8 af[4], bfv[4];
    #pragma unroll
    for (int i = 0; i < 4; ++i) {
      int row = wm * 64 + i * 16 + lr;
      f32x4 a0 = *(const f32x4*)&As[row * BK + ls * 8];
      f32x4 a1 = *(const f32x4*)&As[row * BK + ls * 8 + 4];
      af[i] = pack8(a0, a1);
    }
    #pragma unroll
    for (int j = 0; j < 4; ++j)
      bfv[j] = *(const bf16x8*)&Bs[(wn * 64 + j * 16 + lr) * BK + ls * 8];
    #pragma unroll
    for (int i = 0; i < 4; ++i)
      #pragma unroll
      for (int j = 0; j < 4; ++j)
        acc[i][j] = __builtin_amdgcn_mfma_f32_16x16x32_bf16(af[i], bfv[j], acc[i][j], 0, 0, 0);
    __syncthreads();
  }

  const int pc = tileN + wn * 64;
  #pragma unroll
  for (int i = 0; i < 4; ++i) {
    #pragma unroll
    for (int tt = 0; tt < 2; ++tt) {
      int col = (pc >> 1) + tt * 16 + lr;
      #pragma unroll
      for (int rr = 0; rr < 4; ++rr) {
        int row = tileM + wm * 64 + i * 16 + ls * 4 + rr;
        float th = ftanh_(acc[i][2 * tt][rr]     + bW[col]);
        float tc = ftanh_(acc[i][2 * tt + 1][rr] + bW[256 + col]);
        size_t node = (size_t)LEAF0 + row;
        hout[node * HSZ + col] = th;
        cbuf[node * HSZ + col] = tc;
      }
    }
  }
}

// ---------------------------------------------------------------------------
// One tree level, fused: gates = h_cat(m x 512 f32, contiguous slab) @ Uperm + bU;
// gate-permuted N frags -> i,o,u,f in-register; c_new/h_new written directly.
// ---------------------------------------------------------------------------
__global__ __launch_bounds__(256) void k_level(
    float* __restrict__ hbuf, float* __restrict__ cbuf,
    const unsigned short* __restrict__ Ut, const float* __restrict__ bU,
    int a, int m)
{
  __shared__ __attribute__((aligned(16))) float          As[BM * BK];   // 16 KB
  __shared__ __attribute__((aligned(16))) unsigned short Bs[BM * BK];   //  8 KB
  const int t = threadIdx.x;
  const int lane = t & 63, w = t >> 6;
  const int wm = w >> 1, wn = w & 1;
  const int lr = lane & 15, ls = lane >> 4;

  const int nwg = gridDim.x;
  const int wg = (blockIdx.x & 7) * (nwg >> 3) + (blockIdx.x >> 3);
  const int mblk = wg >> 3, nblk = wg & 7;
  const int tileM = mblk * BM, tileN = nblk * 128;

  f32x4 acc[4][4];
  #pragma unroll
  for (int i = 0; i < 4; ++i)
    #pragma unroll
    for (int j = 0; j < 4; ++j)
      #pragma unroll
      for (int e = 0; e < 4; ++e) acc[i][j][e] = 0.f;

  const float* Abase = hbuf + (size_t)(2 * a + 1) * HSZ + (size_t)tileM * 512;
  const unsigned short* Bbase = Ut + (size_t)tileN * KU;

  const int arow = lane >> 3, acolv = (lane & 7) * 4;
  const int brow = lane >> 2, bcolv = (lane & 3) * 8;

  for (int k0 = 0; k0 < KU; k0 += BK) {
    #pragma unroll
    for (int s = 0; s < 4; ++s) {
      int e = w * 4 + s;
      const float* g = Abase + (size_t)(e * 8 + arow) * 512 + k0 + acolv;
      gld_lds16(g, (char*)As + e * 1024);
    }
    #pragma unroll
    for (int s = 0; s < 2; ++s) {
      int e = w * 2 + s;
      const unsigned short* g = Bbase + (size_t)(e * 16 + brow) * KU + k0 + bcolv;
      gld_lds16(g, (char*)Bs + e * 1024);
    }
    __syncthreads();
    bf16x8 af[4], bfv[4];
    #pragma unroll
    for (int i = 0; i < 4; ++i) {
      int row = wm * 64 + i * 16 + lr;
      f32x4 a0 = *(const f32x4*)&As[row * BK + ls * 8];
      f32x4 a1 = *(const f32x4*)&As[row * BK + ls * 8 + 4];
      af[i] = pack8(a0, a1);
    }
    #pragma unroll
    for (int j = 0; j < 4; ++j)
      bfv[j] = *(const bf16x8*)&Bs[(wn * 64 + j * 16 + lr) * BK + ls * 8];
    #pragma unroll
    for (int i = 0; i < 4; ++i)
      #pragma unroll
      for (int j = 0; j < 4; ++j)
        acc[i][j] = __builtin_amdgcn_mfma_f32_16x16x32_bf16(af[i], bfv[j], acc[i][j], 0, 0, 0);
    __syncthreads();
  }

  const int pc = tileN + wn * 64;            // frag j == gate g within this 64-col span
  const int col = (pc >> 2) + lr;            // h-dim column 0..255
  const float bi = bU[col], bo = bU[256 + col], bu = bU[512 + col], bff = bU[768 + col];
  #pragma unroll
  for (int i = 0; i < 4; ++i) {
    #pragma unroll
    for (int rr = 0; rr < 4; ++rr) {
      int noderow = tileM + wm * 64 + i * 16 + ls * 4 + rr;
      if (noderow < m) {
        float iv = fsig  (acc[i][0][rr] + bi);
        float ov = fsig  (acc[i][1][rr] + bo);
        float uv = ftanh_(acc[i][2][rr] + bu);
        float fv = fsig  (acc[i][3][rr] + bff);
        size_t node = (size_t)a + noderow;
        float cl = cbuf[(2 * node + 1) * HSZ + col];
        float cr = cbuf[(2 * node + 2) * HSZ + col];
        float cn = iv * uv + fv * (cl + cr);
        float hn = ov * ftanh_(cn);
        hbuf[node * HSZ + col] = hn;
        cbuf[node * HSZ + col] = cn;
      }
    }
  }
}

// ---------------------------------------------------------------------------
extern "C" void kernel_launch(void* const* d_in, const int* in_sizes, int n_in,
                              void* d_out, int out_size, void* d_ws, size_t ws_size,
                              hipStream_t stream) {
  const float* x  = (const float*)d_in[0];
  const float* W  = (const float*)d_in[1];
  const float* bW = (const float*)d_in[2];
  const float* U  = (const float*)d_in[3];
  const float* bU = (const float*)d_in[4];
  // d_in[5] = children (int32) — structurally 2i+1/2i+2 (complete binary tree).
  float* hout = (float*)d_out;
  char*  ws   = (char*)d_ws;

  float* cbuf = (float*)ws;                                   // 268,434,432 B
  size_t coff = (size_t)N_NODES * HSZ * sizeof(float);
  unsigned short* Ut = (unsigned short*)(ws + coff);          // 1 MiB
  unsigned short* Wt = (unsigned short*)(ws + coff + (size_t)GATES * KU * 2);

  const int preptot = GATES * KU + WCOLS * KX;
  hipLaunchKernelGGL(k_prep, dim3((preptot + 255) / 256), dim3(256), 0, stream, W, U, Wt, Ut);

  hipLaunchKernelGGL(k_init, dim3((N_LEAF / BM) * 4), dim3(256), 0, stream,
                     x, Wt, bW, hout, cbuf);

  for (int d = 16; d >= 0; --d) {
    int m = 1 << d;
    int a = m - 1;
    int mb = (m + BM - 1) / BM;
    hipLaunchKernelGGL(k_level, dim3(mb * 8), dim3(256), 0, stream,
                       hout, cbuf, Ut, bU, a, m);
  }
}